// Round 1
// 1663.331 us; speedup vs baseline: 1.0206x; 1.0206x over previous
//
#include <hip/hip_runtime.h>

// ---------------------------------------------------------------------------
// HierarchicalTargetAttention on MI355X (gfx950)
// B=4, d=512, L=4096, C1=1168 cats, NL=8929 labels.
// All heavy math via bf16 MFMA (16x16x32), fp32 accumulate, fp32 softmax.
// gemm_bt (128x128, 2-barrier) for small/odd shapes; gemm8_bt (256x256,
// ring-3 LDS, counted-vmcnt pipeline, swizzled LDS) for the big E2 GEMM.
// ---------------------------------------------------------------------------

#define RSCALE 0.04419417382415922f  // 1/sqrt(512)

typedef __attribute__((ext_vector_type(8))) short bf16x8;
typedef __attribute__((ext_vector_type(4))) float f32x4;

__device__ __forceinline__ ushort f2bf(float x) {
  union { float f; unsigned u; } c; c.f = x;
  unsigned u = c.u;
  return (ushort)((u + 0x7fffu + ((u >> 16) & 1u)) >> 16);
}

__device__ __forceinline__ void gl_lds16(const ushort* g, ushort* l) {
  __builtin_amdgcn_global_load_lds(
      (const __attribute__((address_space(1))) unsigned*)g,
      (__attribute__((address_space(3))) unsigned*)l, 16, 0, 0);
}

// ---------------------------------------------------------------------------
// gemm_bt: C[m,n] = epi(sum_k A[m,k] * B[n,k])
// A: [Ma x K] bf16 row-major, B: [N x K] bf16 row-major. 128x128 tile, BK=32.
// Block 256 = 4 waves in 2x2, each wave 64x64 (4x4 MFMA 16x16x32).
// A-row staging clamped to M-1 (edge tiles), stores guarded by row<M.
// EPI: 0 = f32 store; 1 = f32*RSCALE; 2 = bf16(elu(x + bias[col])).
// ---------------------------------------------------------------------------
template <int EPI>
__global__ __launch_bounds__(256) void gemm_bt(
    const ushort* __restrict__ A, const ushort* __restrict__ B,
    void* __restrict__ Cv, const float* __restrict__ bias,
    int M, int N, int K, long long sA, long long sB, long long sC) {
  __shared__ ushort ldsA[128 * 32];
  __shared__ ushort ldsB[128 * 32];
  const int tid = threadIdx.x;
  const int wave = tid >> 6, lane = tid & 63;
  const int m0 = blockIdx.y * 128, n0 = blockIdx.x * 128;
  const int z = blockIdx.z;
  A += (size_t)z * sA;
  B += (size_t)z * sB;

  // staging: each wave-issue copies 16 rows x 32 cols (1024B) via lane*16B
  const int lr = lane >> 2;
  const int lcol = (lane & 3) * 8;
  int rA0 = m0 + wave * 16 + lr;      if (rA0 > M - 1) rA0 = M - 1;
  int rA1 = m0 + 64 + wave * 16 + lr; if (rA1 > M - 1) rA1 = M - 1;
  const int rB0 = n0 + wave * 16 + lr;
  const int rB1 = n0 + 64 + wave * 16 + lr;
  const ushort* pA0 = A + (size_t)rA0 * K + lcol;
  const ushort* pA1 = A + (size_t)rA1 * K + lcol;
  const ushort* pB0 = B + (size_t)rB0 * K + lcol;
  const ushort* pB1 = B + (size_t)rB1 * K + lcol;
  ushort* dA0 = ldsA + wave * 512;
  ushort* dA1 = ldsA + 2048 + wave * 512;
  ushort* dB0 = ldsB + wave * 512;
  ushort* dB1 = ldsB + 2048 + wave * 512;

  const int wm = (wave >> 1) * 64, wn = (wave & 1) * 64;
  const ushort* aBase = ldsA + (wm + (lane & 15)) * 32 + (lane >> 4) * 8;
  const ushort* bBase = ldsB + (wn + (lane & 15)) * 32 + (lane >> 4) * 8;

  f32x4 acc[4][4];
  f32x4 z4 = {0.f, 0.f, 0.f, 0.f};
#pragma unroll
  for (int i = 0; i < 4; i++)
#pragma unroll
    for (int j = 0; j < 4; j++) acc[i][j] = z4;

  for (int k0 = 0; k0 < K; k0 += 32) {
    __syncthreads();
    gl_lds16(pA0 + k0, dA0);
    gl_lds16(pA1 + k0, dA1);
    gl_lds16(pB0 + k0, dB0);
    gl_lds16(pB1 + k0, dB1);
    __syncthreads();
    bf16x8 af[4], bv[4];
#pragma unroll
    for (int i = 0; i < 4; i++) af[i] = *(const bf16x8*)(aBase + i * 512);
#pragma unroll
    for (int i = 0; i < 4; i++) bv[i] = *(const bf16x8*)(bBase + i * 512);
#pragma unroll
    for (int mi = 0; mi < 4; mi++)
#pragma unroll
      for (int ni = 0; ni < 4; ni++)
        acc[mi][ni] = __builtin_amdgcn_mfma_f32_16x16x32_bf16(
            af[mi], bv[ni], acc[mi][ni], 0, 0, 0);
  }

  // C/D layout: col = lane&15, row = (lane>>4)*4 + r  (m89-verified)
  const int cc = lane & 15;
  const int cr = (lane >> 4) * 4;
  float* Cf = (float*)Cv + (size_t)z * sC;
  ushort* Cb = (ushort*)Cv + (size_t)z * sC;
#pragma unroll
  for (int mi = 0; mi < 4; mi++) {
#pragma unroll
    for (int ni = 0; ni < 4; ni++) {
      const int col = n0 + wn + ni * 16 + cc;
#pragma unroll
      for (int r = 0; r < 4; r++) {
        const int row = m0 + wm + mi * 16 + cr + r;
        if (row < M) {
          float x = acc[mi][ni][r];
          if (EPI == 0) {
            Cf[(size_t)row * N + col] = x;
          } else if (EPI == 1) {
            Cf[(size_t)row * N + col] = x * RSCALE;
          } else {
            x += bias[col];
            x = x > 0.f ? x : (__expf(x) - 1.f);
            Cb[(size_t)row * N + col] = f2bf(x);
          }
        }
      }
    }
  }
}

// ---------------------------------------------------------------------------
// gemm8_bt: 256x256 tile, BK=32, 512 threads = 8 waves (2M x 4N), per-wave
// output 128x64 (8x4 MFMA 16x16x32). Ring-3 LDS (96KB) -> 2-deep prefetch
// with counted s_waitcnt vmcnt(4) gates (never drained in steady state).
// LDS XOR swizzle: slot ^= (row>>1)&3 (both-sides: pre-swizzled global src
// for global_load_lds linear dest + swizzled ds_read offset). Requires
// K % 32 == 0 and K >= 64; N tile-exact for best occupancy (1 block/CU).
// ---------------------------------------------------------------------------
template <int EPI>
__global__ __launch_bounds__(512, 2) void gemm8_bt(
    const ushort* __restrict__ A, const ushort* __restrict__ B,
    void* __restrict__ Cv, const float* __restrict__ bias,
    int M, int N, int K, long long sA, long long sB, long long sC) {
  __shared__ ushort lds[3 * 16384];  // 3 bufs x (A 8192 + B 8192) elems = 96KB
  const int tid = threadIdx.x;
  const int wave = tid >> 6, lane = tid & 63;
  const int m0 = blockIdx.y * 256, n0 = blockIdx.x * 256;
  const int z = blockIdx.z;
  A += (size_t)z * sA;
  B += (size_t)z * sB;

  // ---- staging map: one gl_lds issue = 128 rows x 32 cols (8KB) ----
  // lane dest (implicit) = waveBase + lane*16B -> row = wave*16 + (lane>>2),
  // 16B-slot = lane&3. Source col slot pre-swizzled: (lane&3) ^ ((lane>>3)&3)
  const int srow = wave * 16 + (lane >> 2);
  const int scol = ((lane & 3) ^ ((lane >> 3) & 3)) * 8;
  int rA0 = m0 + srow;        if (rA0 > M - 1) rA0 = M - 1;
  int rA1 = m0 + 128 + srow;  if (rA1 > M - 1) rA1 = M - 1;
  int rB0 = n0 + srow;        if (rB0 > N - 1) rB0 = N - 1;
  int rB1 = n0 + 128 + srow;  if (rB1 > N - 1) rB1 = N - 1;
  const ushort* pA0 = A + (size_t)rA0 * K + scol;
  const ushort* pA1 = A + (size_t)rA1 * K + scol;
  const ushort* pB0 = B + (size_t)rB0 * K + scol;
  const ushort* pB1 = B + (size_t)rB1 * K + scol;
  const int wbase = wave * 512;  // wave-uniform LDS dest base within an issue

  // ---- fragment read offsets (elems), swizzled: slot = (l>>4) ^ ((li>>1)&3)
  const int wmi = wave >> 2;   // 0..1 -> rows wmi*128
  const int wni = wave & 3;    // 0..3 -> cols wni*64
  const int li = lane & 15;
  const int slotx = (((lane >> 4) ^ ((li >> 1) & 3)) * 8);
  const int aOff = (wmi * 128 + li) * 32 + slotx;         // + mi*512
  const int bOff = 8192 + (wni * 64 + li) * 32 + slotx;   // + ni*512

  f32x4 acc[8][4];
  f32x4 z4 = {0.f, 0.f, 0.f, 0.f};
#pragma unroll
  for (int i = 0; i < 8; i++)
#pragma unroll
    for (int j = 0; j < 4; j++) acc[i][j] = z4;

  // ---- prologue: stage tiles 0 (buf0) and 1 (buf1), 8 issues ----
  {
    ushort* b0 = lds;
    gl_lds16(pA0, b0 + wbase);
    gl_lds16(pA1, b0 + 4096 + wbase);
    gl_lds16(pB0, b0 + 8192 + wbase);
    gl_lds16(pB1, b0 + 12288 + wbase);
    ushort* b1 = lds + 16384;
    gl_lds16(pA0 + 32, b1 + wbase);
    gl_lds16(pA1 + 32, b1 + 4096 + wbase);
    gl_lds16(pB0 + 32, b1 + 8192 + wbase);
    gl_lds16(pB1 + 32, b1 + 12288 + wbase);
  }
  asm volatile("s_waitcnt vmcnt(4)" ::: "memory");  // tile0 landed; tile1 fly
  __builtin_amdgcn_s_barrier();
  __builtin_amdgcn_sched_barrier(0);

  const int NT = K >> 5;
  int bsel = 0, nsel = 2;
  for (int t = 0; t < NT; ++t) {
    const ushort* cur = lds + bsel * 16384;
    ushort* nxt = lds + nsel * 16384;
    const bool pf = (t + 2) < NT;
    const int kpf = (t + 2) << 5;
    // phase A: issue next-next A staging, read frags, 16 MFMA (rows 0-63)
    if (pf) {
      gl_lds16(pA0 + kpf, nxt + wbase);
      gl_lds16(pA1 + kpf, nxt + 4096 + wbase);
    }
    bf16x8 af[4], bfr[4];
#pragma unroll
    for (int mi = 0; mi < 4; mi++)
      af[mi] = *(const bf16x8*)(cur + aOff + mi * 512);
#pragma unroll
    for (int ni = 0; ni < 4; ni++)
      bfr[ni] = *(const bf16x8*)(cur + bOff + ni * 512);
    __builtin_amdgcn_s_setprio(1);
#pragma unroll
    for (int mi = 0; mi < 4; mi++)
#pragma unroll
      for (int ni = 0; ni < 4; ni++)
        acc[mi][ni] = __builtin_amdgcn_mfma_f32_16x16x32_bf16(
            af[mi], bfr[ni], acc[mi][ni], 0, 0, 0);
    __builtin_amdgcn_s_setprio(0);
    // phase B: issue next-next B staging, read A rows 64-127, 16 MFMA
    if (pf) {
      gl_lds16(pB0 + kpf, nxt + 8192 + wbase);
      gl_lds16(pB1 + kpf, nxt + 12288 + wbase);
    }
    bf16x8 af2[4];
#pragma unroll
    for (int mi = 0; mi < 4; mi++)
      af2[mi] = *(const bf16x8*)(cur + aOff + 2048 + mi * 512);
    __builtin_amdgcn_s_setprio(1);
#pragma unroll
    for (int mi = 0; mi < 4; mi++)
#pragma unroll
      for (int ni = 0; ni < 4; ni++)
        acc[mi + 4][ni] = __builtin_amdgcn_mfma_f32_16x16x32_bf16(
            af2[mi], bfr[ni], acc[mi + 4][ni], 0, 0, 0);
    __builtin_amdgcn_s_setprio(0);
    // gate: all our ds_reads retired (LDS free for overwrite after barrier),
    // next tile's 4 staging loads retired, tile-after's 4 still in flight.
    asm volatile("s_waitcnt lgkmcnt(0)" ::: "memory");
    if (pf) {
      asm volatile("s_waitcnt vmcnt(4)" ::: "memory");
    } else {
      asm volatile("s_waitcnt vmcnt(0)" ::: "memory");
    }
    __builtin_amdgcn_s_barrier();
    __builtin_amdgcn_sched_barrier(0);
    bsel = (bsel == 2) ? 0 : bsel + 1;
    nsel = (nsel == 2) ? 0 : nsel + 1;
  }

  // C/D layout: col = lane&15, row = (lane>>4)*4 + r  (m89-verified)
  const int cc = lane & 15;
  const int cr = (lane >> 4) * 4;
  float* Cf = (float*)Cv + (size_t)z * sC;
  ushort* Cb = (ushort*)Cv + (size_t)z * sC;
#pragma unroll
  for (int mi = 0; mi < 8; mi++) {
#pragma unroll
    for (int ni = 0; ni < 4; ni++) {
      const int col = n0 + wni * 64 + ni * 16 + cc;
#pragma unroll
      for (int r = 0; r < 4; r++) {
        const int row = m0 + wmi * 128 + mi * 16 + cr + r;
        if (row < M) {
          float x = acc[mi][ni][r];
          if (EPI == 0) {
            Cf[(size_t)row * N + col] = x;
          } else if (EPI == 1) {
            Cf[(size_t)row * N + col] = x * RSCALE;
          } else {
            x += bias[col];
            x = x > 0.f ? x : (__expf(x) - 1.f);
            Cb[(size_t)row * N + col] = f2bf(x);
          }
        }
      }
    }
  }
}

// ---------------------------------------------------------------------------
// Row softmax over 4096 cols. One 256-thread block per row, 16 elems/thread.
// Optional fp32 output (may alias X; per-thread load-before-store) + bf16 out.
// ---------------------------------------------------------------------------
__global__ __launch_bounds__(256) void softmax_rows(const float* X, float* Yf,
                                                    ushort* __restrict__ Ybf) {
  const size_t row = blockIdx.x;
  const int tid = threadIdx.x;
  const float4* xr = (const float4*)(X + row * 4096);
  float4 v[4];
  float m = -3.4e38f;
#pragma unroll
  for (int i = 0; i < 4; i++) {
    v[i] = xr[tid + 256 * i];
    m = fmaxf(m, fmaxf(fmaxf(v[i].x, v[i].y), fmaxf(v[i].z, v[i].w)));
  }
#pragma unroll
  for (int o = 32; o >= 1; o >>= 1) m = fmaxf(m, __shfl_xor(m, o));
  __shared__ float sred[4];
  __shared__ float sred2[4];
  const int wave = tid >> 6, lane = tid & 63;
  if (lane == 0) sred[wave] = m;
  __syncthreads();
  m = fmaxf(fmaxf(sred[0], sred[1]), fmaxf(sred[2], sred[3]));
  float4 e[4];
  float s = 0.f;
#pragma unroll
  for (int i = 0; i < 4; i++) {
    e[i].x = __expf(v[i].x - m);
    e[i].y = __expf(v[i].y - m);
    e[i].z = __expf(v[i].z - m);
    e[i].w = __expf(v[i].w - m);
    s += e[i].x + e[i].y + e[i].z + e[i].w;
  }
#pragma unroll
  for (int o = 32; o >= 1; o >>= 1) s += __shfl_xor(s, o);
  if (lane == 0) sred2[wave] = s;
  __syncthreads();
  s = sred2[0] + sred2[1] + sred2[2] + sred2[3];
  const float inv = 1.f / s;
  float4* yf = Yf ? (float4*)(Yf + row * 4096) : nullptr;
  ushort4* yb = (ushort4*)(Ybf + row * 4096);
#pragma unroll
  for (int i = 0; i < 4; i++) {
    float4 w;
    w.x = e[i].x * inv; w.y = e[i].y * inv;
    w.z = e[i].z * inv; w.w = e[i].w * inv;
    if (yf) yf[tid + 256 * i] = w;
    ushort4 u;
    u.x = f2bf(w.x); u.y = f2bf(w.y); u.z = f2bf(w.z); u.w = f2bf(w.w);
    yb[tid + 256 * i] = u;
  }
}

// src [R][C] f32 -> dst [C][R] bf16, per z-batch offset R*C
__global__ __launch_bounds__(256) void transpose_f32_bf16(
    const float* __restrict__ src, ushort* __restrict__ dst, int R, int C) {
  __shared__ float t[32][33];
  const size_t boff = (size_t)blockIdx.z * R * C;
  const int r0 = blockIdx.y * 32, c0 = blockIdx.x * 32;
  const int tx = threadIdx.x & 31, ty = threadIdx.x >> 5;
#pragma unroll
  for (int j = ty; j < 32; j += 8)
    t[j][tx] = src[boff + (size_t)(r0 + j) * C + c0 + tx];
  __syncthreads();
#pragma unroll
  for (int j = ty; j < 32; j += 8)
    dst[boff + (size_t)(c0 + j) * R + r0 + tx] = f2bf(t[tx][j]);
}

// src [R][C] bf16 -> dst [C][R] bf16 (pass-through)
__global__ __launch_bounds__(256) void transpose_u16(
    const ushort* __restrict__ src, ushort* __restrict__ dst, int R, int C) {
  __shared__ ushort t[32][33];
  const size_t boff = (size_t)blockIdx.z * R * C;
  const int r0 = blockIdx.y * 32, c0 = blockIdx.x * 32;
  const int tx = threadIdx.x & 31, ty = threadIdx.x >> 5;
#pragma unroll
  for (int j = ty; j < 32; j += 8)
    t[j][tx] = src[boff + (size_t)(r0 + j) * C + c0 + tx];
  __syncthreads();
#pragma unroll
  for (int j = ty; j < 32; j += 8)
    dst[boff + (size_t)(c0 + j) * R + r0 + tx] = t[tx][j];
}

__global__ __launch_bounds__(256) void cvt_f32_bf16_k(
    const float* __restrict__ s, ushort* __restrict__ dst, int n4) {
  const int t = blockIdx.x * 256 + threadIdx.x;
  if (t >= n4) return;
  const float4 v = ((const float4*)s)[t];
  ushort4 o;
  o.x = f2bf(v.x); o.y = f2bf(v.y); o.z = f2bf(v.z); o.w = f2bf(v.w);
  ((ushort4*)dst)[t] = o;
}

// Q2b[b,n,:] = bf16(Q2[n,:] + C1[b, map[n], :])
__global__ __launch_bounds__(256) void build_q2b(
    const float* __restrict__ Q2, const float* __restrict__ C1,
    const int* __restrict__ cmap, ushort* __restrict__ out) {
  const long long t = (long long)blockIdx.x * 256 + threadIdx.x;
  if (t >= 4LL * 8929 * 128) return;
  const int c4 = (int)(t & 127);
  const long long rowid = t >> 7;
  const int n = (int)(rowid % 8929);
  const int b = (int)(rowid / 8929);
  const float4 q = ((const float4*)(Q2 + (size_t)n * 512))[c4];
  const int cat = cmap[n];
  const float4 c = ((const float4*)(C1 + ((size_t)b * 1168 + cat) * 512))[c4];
  ushort4 o;
  o.x = f2bf(q.x + c.x); o.y = f2bf(q.y + c.y);
  o.z = f2bf(q.z + c.z); o.w = f2bf(q.w + c.w);
  ((ushort4*)(out + ((size_t)b * 8929 + n) * 512))[c4] = o;
}

extern "C" void kernel_launch(void* const* d_in, const int* in_sizes, int n_in,
                              void* d_out, int out_size, void* d_ws,
                              size_t ws_size, hipStream_t stream) {
  const float* H = (const float*)d_in[0];
  const float* Wk = (const float*)d_in[1];
  const float* bk = (const float*)d_in[2];
  const float* Wv = (const float*)d_in[3];
  const float* bv = (const float*)d_in[4];
  const float* Q1 = (const float*)d_in[5];
  const float* Q2 = (const float*)d_in[6];
  const int* cmap = (const int*)d_in[7];

  const int Bn = 4, d = 512, L = 4096, C1n = 1168, NL = 8929;

  char* w = (char*)d_ws;
  size_t off = 0;
  auto alloc = [&](size_t bytes) { void* p = w + off; off += bytes; return p; };
  ushort* Hb  = (ushort*)alloc((size_t)Bn * L * d * 2);   // H^T, [B][L][d]
  ushort* Kb  = (ushort*)alloc((size_t)Bn * L * d * 2);   // K,   [B][L][d]
  ushort* Vb  = (ushort*)alloc((size_t)Bn * L * d * 2);   // V,   [B][L][d]
  ushort* Vt  = (ushort*)alloc((size_t)Bn * d * L * 2);   // V^T, [B][d][L]
  ushort* Wkb = (ushort*)alloc((size_t)d * d * 2);
  ushort* Wvb = (ushort*)alloc((size_t)d * d * 2);
  ushort* Q1b = (ushort*)alloc((size_t)C1n * d * 2);
  ushort* A1b = (ushort*)alloc((size_t)Bn * C1n * L * 2);
  float*  C1  = (float*)alloc((size_t)Bn * C1n * d * 4);
  ushort* Q2b = (ushort*)alloc((size_t)Bn * NL * d * 2);
  // scratch slot: E1 (stage 1) then A2-bf16 (stage 2), E1 dead by then
  float*  E1  = (float*)(w + off);
  ushort* A2b = (ushort*)(w + off);
  const size_t e1B = (size_t)Bn * C1n * L * 4;
  const size_t a2bPer = (size_t)NL * L * 2;
  int nb = 1;  // batches per stage-2 group, by available workspace
  if (ws_size >= off + (a2bPer * 4 > e1B ? a2bPer * 4 : e1B)) nb = 4;
  else if (ws_size >= off + (a2bPer * 2 > e1B ? a2bPer * 2 : e1B)) nb = 2;

  float* C2out = (float*)d_out;                       // [B][NL][d]
  float* A2out = (float*)d_out + (size_t)Bn * NL * d; // [B][NL][L]

  // weights / queries to bf16
  cvt_f32_bf16_k<<<dim3((d * d / 4 + 255) / 256), 256, 0, stream>>>(Wk, Wkb, d * d / 4);
  cvt_f32_bf16_k<<<dim3((d * d / 4 + 255) / 256), 256, 0, stream>>>(Wv, Wvb, d * d / 4);
  cvt_f32_bf16_k<<<dim3((C1n * d / 4 + 255) / 256), 256, 0, stream>>>(Q1, Q1b, C1n * d / 4);
  // H [B][d][L] f32 -> Hb [B][L][d] bf16
  transpose_f32_bf16<<<dim3(L / 32, d / 32, Bn), 256, 0, stream>>>(H, Hb, d, L);
  // K = elu(Hb*Wk^T + bk), V = elu(Hb*Wv^T + bv)   (M = B*L flattened)
  gemm_bt<2><<<dim3(d / 128, (Bn * L) / 128, 1), 256, 0, stream>>>(
      Hb, Wkb, Kb, bk, Bn * L, d, d, 0, 0, 0);
  gemm_bt<2><<<dim3(d / 128, (Bn * L) / 128, 1), 256, 0, stream>>>(
      Hb, Wvb, Vb, bv, Bn * L, d, d, 0, 0, 0);
  // Vt = V^T per batch
  transpose_u16<<<dim3(d / 32, L / 32, Bn), 256, 0, stream>>>(Vb, Vt, L, d);
  // E1[b,c,l] = Q1.Kb /SCALE
  gemm_bt<1><<<dim3(L / 128, (C1n + 127) / 128, Bn), 256, 0, stream>>>(
      Q1b, Kb, E1, nullptr, C1n, L, d, 0, (long long)L * d, (long long)C1n * L);
  // A1 = softmax(E1) -> bf16
  softmax_rows<<<dim3(Bn * C1n), 256, 0, stream>>>(E1, nullptr, A1b);
  // C1[b,c,d] = A1 . Vt
  gemm_bt<0><<<dim3(d / 128, (C1n + 127) / 128, Bn), 256, 0, stream>>>(
      A1b, Vt, C1, nullptr, C1n, d, L, (long long)C1n * L, (long long)d * L,
      (long long)C1n * d);
  // Q2b = bf16(Q2 + C1[map])
  build_q2b<<<dim3(17858), 256, 0, stream>>>(Q2, C1, cmap, Q2b);

  // stage 2, grouped by workspace tier
  for (int g = 0; g < Bn / nb; ++g) {
    const ushort* Qg = Q2b + (size_t)g * nb * NL * d;
    const ushort* Kg = Kb + (size_t)g * nb * L * d;
    const ushort* Vtg = Vt + (size_t)g * nb * d * L;
    float* Eg = A2out + (size_t)g * nb * NL * L;
    float* Cg = C2out + (size_t)g * nb * NL * d;
    // E2 -> A2 region (f32, /SCALE fused) — 256x256 pipelined GEMM
    gemm8_bt<1><<<dim3(L / 256, (NL + 255) / 256, nb), 512, 0, stream>>>(
        Qg, Kg, Eg, nullptr, NL, L, d, (long long)NL * d, (long long)L * d,
        (long long)NL * L);
    // softmax in place (f32) + bf16 copy for the C2 GEMM
    softmax_rows<<<dim3(nb * NL), 256, 0, stream>>>(Eg, Eg, A2b);
    // C2 = A2 . Vt
    gemm_bt<0><<<dim3(d / 128, (NL + 127) / 128, nb), 256, 0, stream>>>(
        A2b, Vtg, Cg, nullptr, NL, d, L, (long long)NL * L, (long long)d * L,
        (long long)NL * d);
  }
}